// Round 20
// baseline (68.951 us; speedup 1.0000x reference)
//
#include <hip/hip_runtime.h>
#include <math.h>

static constexpr int N   = 4096;  // IN_SIZE
static constexpr int H   = 5;     // HID
static constexpr int NO  = 2048;  // OUT_SIZE
static constexpr float FEPS = 1e-4f;
static constexpr int NJC  = 4;          // j-chunks (256 float4-cols each)
static constexpr int NIG  = 128;        // i-groups (32 rows each)
static constexpr int RPB  = N / NIG;    // 32 rows per block
static constexpr int NBLK = NIG * NJC;  // 512 blocks (2/CU)
static constexpr int CR   = 8;          // rows per staged chunk
static constexpr int NCH  = RPB / CR;   // 4 chunks
static constexpr int CF4  = CR * 256;   // 2048 float4s per chunk (32 KB)
static constexpr int NCON = 256;        // k_out blocks
static constexpr int NR   = NO / NCON;  // 8 output rows per k_out block

#if __has_builtin(__builtin_amdgcn_rcpf)
__device__ __forceinline__ float frcp(float x) { return __builtin_amdgcn_rcpf(x); }
#else
__device__ __forceinline__ float frcp(float x) { return 1.0f / x; }
#endif
#if __has_builtin(__builtin_amdgcn_rsqf)
__device__ __forceinline__ float frsq(float x) { return __builtin_amdgcn_rsqf(x); }
#else
__device__ __forceinline__ float frsq(float x) { return 1.0f / sqrtf(x); }
#endif

__device__ __forceinline__ float wave_reduce(float v) {
#pragma unroll
    for (int o = 32; o > 0; o >>= 1) v += __shfl_down(v, o, 64);
    return v;
}

// K1: 2-D tiled partial of M[a][b] = sum_{i,j} W1[i,a] X[i,j] W1[j,b].
// R13 geometry + ASYNC global_load_lds staging of X: 4 chunks of 8 rows
// (32 KB) through a 64 KB LDS double-buffer. Each wave issues 8 width-16
// global_load_lds per chunk (no VGPR round-trip -> loads stay in flight
// while VALU consumes the previous chunk from LDS). LDS layout is linear
// in lane order (wave-uniform dest + lane*16), matching consumption
// xs[r*256+t] (consecutive 16B/lane, conflict-free).
__global__ __launch_bounds__(256) void k_xw1(const float* __restrict__ X,
                                             const float* __restrict__ W1,
                                             float* __restrict__ Mp) {
    const int b    = blockIdx.x;
    const int ig   = b >> 2;        // 128 i-groups
    const int jcb  = b & 3;         // 4 j-chunks
    const int t    = threadIdx.x;
    const int w    = t >> 6, lane = t & 63;
    const int j4   = jcb * 256 + t; // this thread's float4 column
    const float4* W14 = reinterpret_cast<const float4*>(W1);
    const float4* X4  = reinterpret_cast<const float4*>(X);
    const int i0   = ig * RPB;

    __shared__ float4 xs[2][CF4];   // 2 x 32 KB double buffer

    // ---- issue chunk 0 staging (async, no VGPR round trip) ----
#pragma unroll
    for (int k = 0; k < 8; ++k) {
        const int c = w * 512 + k * 64 + lane;          // chunk f4 index
        const float4* gp = X4 + (size_t)(i0 + (c >> 8)) * (N / 4)
                              + jcb * 256 + (c & 255);
        __builtin_amdgcn_global_load_lds(gp, &xs[0][w * 512 + k * 64], 16, 0, 0);
    }

    // ---- wf[20] gather overlaps chunk-0 flight ----
    float wf[20];
    {
        const float4 f0 = W14[5 * j4 + 0];
        const float4 f1 = W14[5 * j4 + 1];
        const float4 f2 = W14[5 * j4 + 2];
        const float4 f3 = W14[5 * j4 + 3];
        const float4 f4 = W14[5 * j4 + 4];
        wf[0]=f0.x;  wf[1]=f0.y;  wf[2]=f0.z;  wf[3]=f0.w;
        wf[4]=f1.x;  wf[5]=f1.y;  wf[6]=f1.z;  wf[7]=f1.w;
        wf[8]=f2.x;  wf[9]=f2.y;  wf[10]=f2.z; wf[11]=f2.w;
        wf[12]=f3.x; wf[13]=f3.y; wf[14]=f3.z; wf[15]=f3.w;
        wf[16]=f4.x; wf[17]=f4.y; wf[18]=f4.z; wf[19]=f4.w;
    }

    float pm[H][H];
#pragma unroll
    for (int a = 0; a < H; ++a)
#pragma unroll
        for (int bb = 0; bb < H; ++bb) pm[a][bb] = 0.f;

    __syncthreads();   // chunk 0 landed (vmcnt drained)

#pragma unroll
    for (int ch = 0; ch < NCH; ++ch) {
        // issue next chunk's staging into the other buffer (in flight
        // across this chunk's consume; drained at the end barrier)
        if (ch < NCH - 1) {
#pragma unroll
            for (int k = 0; k < 8; ++k) {
                const int c = w * 512 + k * 64 + lane;
                const float4* gp = X4 + (size_t)(i0 + (ch + 1) * CR + (c >> 8)) * (N / 4)
                                      + jcb * 256 + (c & 255);
                __builtin_amdgcn_global_load_lds(gp, &xs[(ch + 1) & 1][w * 512 + k * 64],
                                                 16, 0, 0);
            }
        }
        // consume current chunk from LDS
#pragma unroll
        for (int r = 0; r < CR; ++r) {
            const int row = i0 + ch * CR + r;
            const float4 x = xs[ch & 1][r * 256 + t];
            float t5[H];
#pragma unroll
            for (int a = 0; a < H; ++a)
                t5[a] = x.x * wf[a]      + x.y * wf[5 + a]
                      + x.z * wf[10 + a] + x.w * wf[15 + a];
            float w1r[H];
#pragma unroll
            for (int a = 0; a < H; ++a) w1r[a] = W1[(size_t)row * H + a];
#pragma unroll
            for (int a = 0; a < H; ++a)
#pragma unroll
                for (int bb = 0; bb < H; ++bb) pm[a][bb] += w1r[a] * t5[bb];
        }
        __syncthreads();   // next chunk landed; buffer safe to reuse
    }

    __shared__ float sm[4][25];
    {
#pragma unroll
        for (int a = 0; a < H; ++a)
#pragma unroll
            for (int bb = 0; bb < H; ++bb) {
                const float v = wave_reduce(pm[a][bb]);
                if (lane == 0) sm[w][a * H + bb] = v;
            }
    }
    __syncthreads();
    if (t < 25)
        Mp[b * 25 + t] = sm[0][t] + sm[1][t] + sm[2][t] + sm[3][t];
}

// Lane-parallel Jacobi rotation, compile-time (p,q). Lane L (<25) holds
// a = A[L/5][L%5], u = U[L/5][L%5].
#define JROT(p, q)                                                            \
    {                                                                         \
        const float apq = __shfl(a, (p) * 5 + (q), 64);                       \
        const float app = __shfl(a, (p) * 5 + (p), 64);                       \
        const float aqq = __shfl(a, (q) * 5 + (q), 64);                       \
        const bool  skip =                                                    \
            (apq * apq) <= (1e-26f * (app * app + aqq * aqq) + 1e-38f);       \
        const float theta = (aqq - app) * frcp(2.0f * apq);                   \
        const float tden  = fabsf(theta) + sqrtf(theta * theta + 1.0f);       \
        const float ttv   = ((theta >= 0.0f) ? 1.0f : -1.0f) * frcp(tden);    \
        float cc = frsq(ttv * ttv + 1.0f);                                    \
        float ss = ttv * cc;                                                  \
        cc = skip ? 1.0f : cc;                                                \
        ss = skip ? 0.0f : ss;                                                \
        {                                                                     \
            const int  pr   = ((r == (p)) ? (q) : ((r == (q)) ? (p) : r));    \
            const float prt = __shfl(a, pr * 5 + c, 64);                      \
            a = (r == (p)) ? (cc * a - ss * prt)                              \
                           : ((r == (q)) ? (ss * prt + cc * a) : a);          \
        }                                                                     \
        {                                                                     \
            const int  pc   = ((c == (p)) ? (q) : ((c == (q)) ? (p) : c));    \
            const float prt = __shfl(a, r * 5 + pc, 64);                      \
            a = (c == (p)) ? (cc * a - ss * prt)                              \
                           : ((c == (q)) ? (ss * prt + cc * a) : a);          \
            const float urt = __shfl(u, r * 5 + pc, 64);                      \
            u = (c == (p)) ? (cc * u - ss * urt)                              \
                           : ((c == (q)) ? (ss * urt + cc * u) : u);          \
        }                                                                     \
    }

// K2: R19's k_out — W2 loads issued at entry (independent of Mp, hide
// under the redundant Mp-reduce + Jacobi), then streaming Z epilogue.
__global__ __launch_bounds__(256) void k_out(const float* __restrict__ Mp,
                                             const float* __restrict__ W2,
                                             float* __restrict__ Z) {
    __shared__ float sred[10][26];
    __shared__ float Msum[25];
    __shared__ float ys[25];
    const int t = threadIdx.x;
    const int i0 = blockIdx.x * NR;

    float4 w2j[2][H];
    float  wcol[NR][H];
#pragma unroll
    for (int hh = 0; hh < 2; ++hh) {
        const int jj = (hh * 256 + t) * 4;
#pragma unroll
        for (int m = 0; m < H; ++m)
            w2j[hh][m] = *reinterpret_cast<const float4*>(W2 + (size_t)m * NO + jj);
    }
#pragma unroll
    for (int r = 0; r < NR; ++r)
#pragma unroll
        for (int k = 0; k < H; ++k) wcol[r][k] = W2[(size_t)k * NO + i0 + r];

    if (t < 250) {
        const int e = t % 25, g = t / 25;
        float s = 0.f;
#pragma unroll 8
        for (int p = g; p < NBLK; p += 10) s += Mp[p * 25 + e];
        sred[g][e] = s;
    }
    __syncthreads();
    if (t < 25) {
        float s = 0.f;
#pragma unroll
        for (int g = 0; g < 10; ++g) s += sred[g][t];
        Msum[t] = s;
    }
    __syncthreads();

    if (t < 64) {
        const int r = t / 5, c = t % 5;
        const float m = (t < 25) ? Msum[t] : 0.f;
        float a = 0.f;
#pragma unroll
        for (int k = 0; k < H; ++k)
            a += __shfl(m, r * 5 + k, 64) * __shfl(m, c * 5 + k, 64);
        float u = (t < 25 && r == c) ? 1.0f : 0.0f;

        for (int sweep = 0; sweep < 6; ++sweep) {
            JROT(0, 1) JROT(0, 2) JROT(0, 3) JROT(0, 4) JROT(1, 2)
            JROT(1, 3) JROT(1, 4) JROT(2, 3) JROT(2, 4) JROT(3, 4)
        }

        const float ev = fmaxf(sqrtf(fmaxf(a, 0.0f)), FEPS);
        float yv = 0.f;
#pragma unroll
        for (int k = 0; k < H; ++k) {
            const float evk = __shfl(ev, 6 * k, 64);
            const float urk = __shfl(u, r * 5 + k, 64);
            const float uck = __shfl(u, c * 5 + k, 64);
            yv += evk * urk * uck;
        }
        if (t < 25) ys[t] = yv - ((r == c) ? FEPS : 0.f);
    }
    __syncthreads();

    float cmat[NR][H];
#pragma unroll
    for (int r = 0; r < NR; ++r)
#pragma unroll
        for (int m = 0; m < H; ++m) {
            float s = 0.f;
#pragma unroll
            for (int k = 0; k < H; ++k) s += wcol[r][k] * ys[k * H + m];
            cmat[r][m] = s;
        }

#pragma unroll
    for (int hh = 0; hh < 2; ++hh) {
        const int jj = (hh * 256 + t) * 4;
#pragma unroll
        for (int r = 0; r < NR; ++r) {
            const int i = i0 + r;
            float zx = 0.f, zy = 0.f, zz = 0.f, zw = 0.f;
#pragma unroll
            for (int m = 0; m < H; ++m) {
                const float cm = cmat[r][m];
                zx += cm * w2j[hh][m].x;
                zy += cm * w2j[hh][m].y;
                zz += cm * w2j[hh][m].z;
                zw += cm * w2j[hh][m].w;
            }
            if (i >= jj && i < jj + 4) {
                if      (i == jj + 0) zx += FEPS;
                else if (i == jj + 1) zy += FEPS;
                else if (i == jj + 2) zz += FEPS;
                else                  zw += FEPS;
            }
            *reinterpret_cast<float4*>(Z + (size_t)i * NO + jj) =
                make_float4(zx, zy, zz, zw);
        }
    }
}

extern "C" void kernel_launch(void* const* d_in, const int* in_sizes, int n_in,
                              void* d_out, int out_size, void* d_ws, size_t ws_size,
                              hipStream_t stream) {
    const float* X  = (const float*)d_in[0];
    const float* W1 = (const float*)d_in[1];
    const float* W2 = (const float*)d_in[2];
    float* out = (float*)d_out;
    float* ws  = (float*)d_ws;

    float* Mp = ws;   // NBLK*25 floats

    hipLaunchKernelGGL(k_xw1, dim3(NBLK), dim3(256), 0, stream, X, W1, Mp);
    hipLaunchKernelGGL(k_out, dim3(NCON), dim3(256), 0, stream, Mp, W2, out);
}

// Round 21
// 40.721 us; speedup vs baseline: 1.6932x; 1.6932x over previous
//
#include <hip/hip_runtime.h>
#include <math.h>

static constexpr int N   = 4096;  // IN_SIZE
static constexpr int H   = 5;     // HID
static constexpr int NO  = 2048;  // OUT_SIZE
static constexpr float FEPS = 1e-4f;
static constexpr int NJC  = 4;          // j-chunks (1024 cols each)
static constexpr int NIG  = 128;        // i-groups (32 rows each)
static constexpr int RPB  = N / NIG;    // 32 rows per block
static constexpr int NBLK = NIG * NJC;  // 512 partial-M blocks (2/CU)
static constexpr int NCON = 256;        // k_out blocks
static constexpr int NR   = NO / NCON;  // 8 output rows per k_out block

#if __has_builtin(__builtin_amdgcn_rcpf)
__device__ __forceinline__ float frcp(float x) { return __builtin_amdgcn_rcpf(x); }
#else
__device__ __forceinline__ float frcp(float x) { return 1.0f / x; }
#endif
#if __has_builtin(__builtin_amdgcn_rsqf)
__device__ __forceinline__ float frsq(float x) { return __builtin_amdgcn_rsqf(x); }
#else
__device__ __forceinline__ float frsq(float x) { return 1.0f / sqrtf(x); }
#endif

__device__ __forceinline__ float wave_reduce(float v) {
#pragma unroll
    for (int o = 32; o > 0; o >>= 1) v += __shfl_down(v, o, 64);
    return v;
}

// K1: 2-D tiled partial of M[a][b] = sum_{i,j} W1[i,a] X[i,j] W1[j,b].
// EXACT R13 kernel (best measured structure). Block (ig,jc): i in
// [ig*32,(ig+1)*32), j4 = jc*256+t. wf[20] loaded once per thread; X
// coalesced read-once; W1 row factors block-uniform scalar loads.
// Six alternative structures (more blocks, manual prefetch, flat stride,
// LDS-staged W1, async global_load_lds) all measured SLOWER: this shape's
// implicit wave-level overlap at 2 blocks/CU is the local optimum.
__global__ __launch_bounds__(256) void k_xw1(const float* __restrict__ X,
                                             const float* __restrict__ W1,
                                             float* __restrict__ Mp) {
    const int b   = blockIdx.x;
    const int ig  = b >> 2;        // 128 i-groups
    const int jcb = b & 3;         // 4 j-chunks
    const int t   = threadIdx.x;
    const int j4  = jcb * 256 + t; // this thread's float4 column
    const float4* W14 = reinterpret_cast<const float4*>(W1);

    float wf[20];
    {
        const float4 f0 = W14[5 * j4 + 0];
        const float4 f1 = W14[5 * j4 + 1];
        const float4 f2 = W14[5 * j4 + 2];
        const float4 f3 = W14[5 * j4 + 3];
        const float4 f4 = W14[5 * j4 + 4];
        wf[0]=f0.x;  wf[1]=f0.y;  wf[2]=f0.z;  wf[3]=f0.w;
        wf[4]=f1.x;  wf[5]=f1.y;  wf[6]=f1.z;  wf[7]=f1.w;
        wf[8]=f2.x;  wf[9]=f2.y;  wf[10]=f2.z; wf[11]=f2.w;
        wf[12]=f3.x; wf[13]=f3.y; wf[14]=f3.z; wf[15]=f3.w;
        wf[16]=f4.x; wf[17]=f4.y; wf[18]=f4.z; wf[19]=f4.w;
    }

    float pm[H][H];
#pragma unroll
    for (int a = 0; a < H; ++a)
#pragma unroll
        for (int bb = 0; bb < H; ++bb) pm[a][bb] = 0.f;

    const int i0 = ig * RPB;
#pragma unroll 4
    for (int r = 0; r < RPB; ++r) {
        const float4 x = reinterpret_cast<const float4*>(
                             X + (size_t)(i0 + r) * N)[j4];
        float t5[H];
#pragma unroll
        for (int a = 0; a < H; ++a)
            t5[a] = x.x * wf[a]      + x.y * wf[5 + a]
                  + x.z * wf[10 + a] + x.w * wf[15 + a];
        float w1r[H];
#pragma unroll
        for (int a = 0; a < H; ++a) w1r[a] = W1[(size_t)(i0 + r) * H + a];
#pragma unroll
        for (int a = 0; a < H; ++a)
#pragma unroll
            for (int bb = 0; bb < H; ++bb) pm[a][bb] += w1r[a] * t5[bb];
    }

    __shared__ float sm[4][25];
    {
        const int lane = t & 63, wv = t >> 6;
#pragma unroll
        for (int a = 0; a < H; ++a)
#pragma unroll
            for (int bb = 0; bb < H; ++bb) {
                const float v = wave_reduce(pm[a][bb]);
                if (lane == 0) sm[wv][a * H + bb] = v;
            }
    }
    __syncthreads();
    if (t < 25)
        Mp[b * 25 + t] = sm[0][t] + sm[1][t] + sm[2][t] + sm[3][t];
}

// Lane-parallel Jacobi rotation, compile-time (p,q). Lane L (<25) holds
// a = A[L/5][L%5], u = U[L/5][L%5].
#define JROT(p, q)                                                            \
    {                                                                         \
        const float apq = __shfl(a, (p) * 5 + (q), 64);                       \
        const float app = __shfl(a, (p) * 5 + (p), 64);                       \
        const float aqq = __shfl(a, (q) * 5 + (q), 64);                       \
        const bool  skip =                                                    \
            (apq * apq) <= (1e-26f * (app * app + aqq * aqq) + 1e-38f);       \
        const float theta = (aqq - app) * frcp(2.0f * apq);                   \
        const float tden  = fabsf(theta) + sqrtf(theta * theta + 1.0f);       \
        const float ttv   = ((theta >= 0.0f) ? 1.0f : -1.0f) * frcp(tden);    \
        float cc = frsq(ttv * ttv + 1.0f);                                    \
        float ss = ttv * cc;                                                  \
        cc = skip ? 1.0f : cc;                                                \
        ss = skip ? 0.0f : ss;                                                \
        {                                                                     \
            const int  pr   = ((r == (p)) ? (q) : ((r == (q)) ? (p) : r));    \
            const float prt = __shfl(a, pr * 5 + c, 64);                      \
            a = (r == (p)) ? (cc * a - ss * prt)                              \
                           : ((r == (q)) ? (ss * prt + cc * a) : a);          \
        }                                                                     \
        {                                                                     \
            const int  pc   = ((c == (p)) ? (q) : ((c == (q)) ? (p) : c));    \
            const float prt = __shfl(a, r * 5 + pc, 64);                      \
            a = (c == (p)) ? (cc * a - ss * prt)                              \
                           : ((c == (q)) ? (ss * prt + cc * a) : a);          \
            const float urt = __shfl(u, r * 5 + pc, 64);                      \
            u = (c == (p)) ? (cc * u - ss * urt)                              \
                           : ((c == (q)) ? (ss * urt + cc * u) : u);          \
        }                                                                     \
    }

// K2: W2 loads (wcol + w2j) issued at kernel ENTRY — independent of Mp,
// their L2/L3 latency hides under the redundant Mp-reduce + Jacobi.
__global__ __launch_bounds__(256) void k_out(const float* __restrict__ Mp,
                                             const float* __restrict__ W2,
                                             float* __restrict__ Z) {
    __shared__ float sred[10][26];
    __shared__ float Msum[25];
    __shared__ float ys[25];
    const int t = threadIdx.x;
    const int i0 = blockIdx.x * NR;

    // ---- issue ALL W2 loads up front (independent of Mp) ----
    float4 w2j[2][H];
    float  wcol[NR][H];
#pragma unroll
    for (int hh = 0; hh < 2; ++hh) {
        const int jj = (hh * 256 + t) * 4;
#pragma unroll
        for (int m = 0; m < H; ++m)
            w2j[hh][m] = *reinterpret_cast<const float4*>(W2 + (size_t)m * NO + jj);
    }
#pragma unroll
    for (int r = 0; r < NR; ++r)
#pragma unroll
        for (int k = 0; k < H; ++k) wcol[r][k] = W2[(size_t)k * NO + i0 + r];

    // ---- redundant Mp reduce (fixed order) + wave0 Jacobi ----
    if (t < 250) {
        const int e = t % 25, g = t / 25;
        float s = 0.f;
#pragma unroll 8
        for (int p = g; p < NBLK; p += 10) s += Mp[p * 25 + e];
        sred[g][e] = s;
    }
    __syncthreads();
    if (t < 25) {
        float s = 0.f;
#pragma unroll
        for (int g = 0; g < 10; ++g) s += sred[g][t];
        Msum[t] = s;
    }
    __syncthreads();

    if (t < 64) {
        const int r = t / 5, c = t % 5;
        const float m = (t < 25) ? Msum[t] : 0.f;
        float a = 0.f;
#pragma unroll
        for (int k = 0; k < H; ++k)
            a += __shfl(m, r * 5 + k, 64) * __shfl(m, c * 5 + k, 64);
        float u = (t < 25 && r == c) ? 1.0f : 0.0f;

        for (int sweep = 0; sweep < 6; ++sweep) {
            JROT(0, 1) JROT(0, 2) JROT(0, 3) JROT(0, 4) JROT(1, 2)
            JROT(1, 3) JROT(1, 4) JROT(2, 3) JROT(2, 4) JROT(3, 4)
        }

        const float ev = fmaxf(sqrtf(fmaxf(a, 0.0f)), FEPS);
        float yv = 0.f;
#pragma unroll
        for (int k = 0; k < H; ++k) {
            const float evk = __shfl(ev, 6 * k, 64);
            const float urk = __shfl(u, r * 5 + k, 64);
            const float uck = __shfl(u, c * 5 + k, 64);
            yv += evk * urk * uck;
        }
        if (t < 25) ys[t] = yv - ((r == c) ? FEPS : 0.f);
    }
    __syncthreads();

    // ---- epilogue: cmat from registers, stream Z ----
    float cmat[NR][H];
#pragma unroll
    for (int r = 0; r < NR; ++r)
#pragma unroll
        for (int m = 0; m < H; ++m) {
            float s = 0.f;
#pragma unroll
            for (int k = 0; k < H; ++k) s += wcol[r][k] * ys[k * H + m];
            cmat[r][m] = s;
        }

#pragma unroll
    for (int hh = 0; hh < 2; ++hh) {
        const int jj = (hh * 256 + t) * 4;
#pragma unroll
        for (int r = 0; r < NR; ++r) {
            const int i = i0 + r;
            float zx = 0.f, zy = 0.f, zz = 0.f, zw = 0.f;
#pragma unroll
            for (int m = 0; m < H; ++m) {
                const float cm = cmat[r][m];
                zx += cm * w2j[hh][m].x;
                zy += cm * w2j[hh][m].y;
                zz += cm * w2j[hh][m].z;
                zw += cm * w2j[hh][m].w;
            }
            if (i >= jj && i < jj + 4) {
                if      (i == jj + 0) zx += FEPS;
                else if (i == jj + 1) zy += FEPS;
                else if (i == jj + 2) zz += FEPS;
                else                  zw += FEPS;
            }
            *reinterpret_cast<float4*>(Z + (size_t)i * NO + jj) =
                make_float4(zx, zy, zz, zw);
        }
    }
}

extern "C" void kernel_launch(void* const* d_in, const int* in_sizes, int n_in,
                              void* d_out, int out_size, void* d_ws, size_t ws_size,
                              hipStream_t stream) {
    const float* X  = (const float*)d_in[0];
    const float* W1 = (const float*)d_in[1];
    const float* W2 = (const float*)d_in[2];
    float* out = (float*)d_out;
    float* ws  = (float*)d_ws;

    float* Mp = ws;   // NBLK*25 floats

    hipLaunchKernelGGL(k_xw1, dim3(NBLK), dim3(256), 0, stream, X, W1, Mp);
    hipLaunchKernelGGL(k_out, dim3(NCON), dim3(256), 0, stream, Mp, W2, out);
}